// Round 5
// baseline (425.834 us; speedup 1.0000x reference)
//
#include <hip/hip_runtime.h>
#include <math.h>

#define NCLS 20
#define IGNORE_IDX 255
#define LOG2E 1.4426950408889634f
#define NTHR 256
#define HALF 256   // voxels per half-tile = NTHR (1 voxel/thread/half)
#define NBLK 512   // 2 blocks/CU (LDS 48.6KB each)
#define NSLOT 32   // global partial-sum slots

__device__ __forceinline__ float wave_reduce(float v) {
#pragma unroll
  for (int off = 32; off > 0; off >>= 1) v += __shfl_xor(v, off, 64);
  return v;
}

__device__ __forceinline__ float neg_log_clamped(float x, bool cond) {
  if (!cond) return 0.0f;
  float xs = fmaxf(x, 1e-38f);
  return fminf(-logf(xs), 100.0f);
}

// Fire-and-forget global->LDS copy: 64 lanes x 16B = 1KB per instr.
// LDS dest is wave-uniform base + lane*16 (HW); global src is per-lane.
__device__ __forceinline__ void gload_lds16(const float* g, float* l) {
  __builtin_amdgcn_global_load_lds(
      (const __attribute__((address_space(1))) void*)g,
      (__attribute__((address_space(3))) void*)l, 16, 0, 0);
}

// r5 design notes:
//  - r0-r4 post-mortem: four structurally different VGPR-dest load kernels
//    all plateau at 1.4-2.5 TB/s delivered, VALU ~11%, ~4KB/CU outstanding
//    (vs 22KB Little's-law need). The invariant is the LOAD PATH, not regs.
//  - Switch to global_load_lds staging (no dest VGPRs, depth limited only
//    by vmcnt): 2-half double-buffer, counted vmcnt(6) so next half's
//    6 ops (1 tgt + 5 stage) stay in flight across the barrier (T4).
//  - Per half: 20 classes x 256 voxels x 4B = 20KB = 20 wave-instrs
//    (5/wave, classes c = wid+4i). LDS row c is exactly one 1KB instr.
//  - Compute: 1 voxel/thread from LDS (stride-1, conflict-free), all
//    transient; per-class sums via fire-and-forget ds_add into
//    s_acc[row][tid&31] (2-way max = free). No per-class register arrays.
//  - 2 blocks/CU: ~40KB continuously outstanding per CU -> HBM-saturating.
__global__ __launch_bounds__(NTHR) void pass1(const float* __restrict__ pred,
                                              const int* __restrict__ target,
                                              float* __restrict__ ws, int N,
                                              int HPB) {
  __shared__ float s_x[2][NCLS * HALF];   // 40 KB
  __shared__ float s_acc[3 * NCLS][32];   // 7.68 KB
  const int tid = threadIdx.x;
  const int wid = tid >> 6;
  const int lane = tid & 63;
  const int sl = tid & 31;

  {
    float* p = &s_acc[0][0];
    for (int i = tid; i < 3 * NCLS * 32; i += NTHR) p[i] = 0.0f;
  }
  __syncthreads();

  const long long g0 = (long long)blockIdx.x * HPB;

  // ---- prologue: target load + stage for half 0 (tgt BEFORE stage so the
  // compiler's wait on tgt use never drains the staging queue).
  int t_next;
  {
    long long nn = g0 * HALF + tid;
    if (nn > N - 1) nn = N - 1;
    t_next = target[nn];
    const int e0 = (int)((g0 * HALF + lane * 4 > (long long)N - 4)
                             ? (long long)N - 4
                             : g0 * HALF + lane * 4);
#pragma unroll
    for (int i = 0; i < 5; ++i) {
      const int c = wid + 4 * i;
      gload_lds16(pred + (size_t)c * N + e0, &s_x[0][c * HALF]);
    }
  }

  for (int it = 0; it < HPB; ++it) {
    const int hb = it & 1;
    const int t_cur = t_next;  // compiler waits vmcnt(5) here: drains only tgt
    const long long g = g0 + it;
    const bool more = (it + 1 < HPB);

    if (more) {  // issue next half's 1 tgt + 5 stage ops
      long long nn = (g + 1) * HALF + tid;
      if (nn > N - 1) nn = N - 1;
      t_next = target[nn];
      const int e0 = (int)(((g + 1) * HALF + lane * 4 > (long long)N - 4)
                               ? (long long)N - 4
                               : (g + 1) * HALF + lane * 4);
#pragma unroll
      for (int i = 0; i < 5; ++i) {
        const int c = wid + 4 * i;
        gload_lds16(pred + (size_t)c * N + e0, &s_x[hb ^ 1][c * HALF]);
      }
      // counted wait: newest 6 (next half) stay in flight; current half done
      asm volatile("s_waitcnt vmcnt(6)" ::: "memory");
    } else {
      asm volatile("s_waitcnt vmcnt(0)" ::: "memory");
    }
    __builtin_amdgcn_sched_barrier(0);
    __syncthreads();

    // ---- compute current half: 1 voxel per thread, all transient
    {
      const float* sx = &s_x[hb][0];
      const long long n = g * HALF + tid;
      const bool in = (n < N);
      float Z = 0.0f, pt = 0.0f;
#pragma unroll
      for (int c = 0; c < NCLS; ++c) {
        const float e =
            __builtin_amdgcn_exp2f(fminf(sx[c * HALF + tid], 80.0f) * LOG2E);
        Z += e;
        pt = (c == t_cur) ? e : pt;
      }
      const bool msk = in && (t_cur != IGNORE_IDX);
      const float w = msk ? __builtin_amdgcn_rcpf(Z) : 0.0f;
      if (msk) {
        atomicAdd(&s_acc[NCLS + t_cur][sl], pt * w);    // nominator
        atomicAdd(&s_acc[2 * NCLS + t_cur][sl], 1.0f);  // ct_count
      }
#pragma unroll
      for (int c = 0; c < NCLS; ++c) {
        const float e =
            __builtin_amdgcn_exp2f(fminf(sx[c * HALF + tid], 80.0f) * LOG2E);
        atomicAdd(&s_acc[c][sl], e * w);  // w==0 for invalid -> adds 0
      }
    }
    __syncthreads();  // protect buf hb from being restaged at it+1
  }

  // block flush: 60 rows x 32 slots, rotated reads (distinct banks/lane)
  if (tid < 3 * NCLS) {
    const float* row = s_acc[tid];
    float v = 0.0f;
#pragma unroll
    for (int i = 0; i < 32; ++i) v += row[(i + tid) & 31];
    // relaxed global atomics; pass2 is a separate dispatch (kernel boundary
    // provides visibility). 32 slots -> chains of NBLK/32 per address.
    atomicAdd(&ws[(size_t)(blockIdx.x & (NSLOT - 1)) * 64 + tid], v);
  }
}

__global__ __launch_bounds__(64) void pass2(const float* __restrict__ ws,
                                            float* __restrict__ out) {
  __shared__ float s[64];
  const int lane = threadIdx.x;
  float a = 0.0f;
#pragma unroll
  for (int r = 0; r < NSLOT; ++r) a += ws[r * 64 + lane];  // 32 indep loads

  // n_masked = sum of ct_count columns (lanes 40..59), uniform collective
  const float n_masked =
      wave_reduce((lane >= 2 * NCLS && lane < 3 * NCLS) ? a : 0.0f);

  s[lane] = a;
  __syncthreads();

  float loss = 0.0f, validf = 0.0f;
  if (lane < NCLS) {
    const float sump = s[lane];
    const float nom = s[NCLS + lane];
    const float cnt = s[2 * NCLS + lane];
    const bool valid = cnt > 0.0f;
    const float prec = nom / fmaxf(sump, 1e-38f);
    const float rec = nom / fmaxf(cnt, 1.0f);
    const float negc = n_masked - cnt;
    const float specn = n_masked - sump - cnt + nom;
    const float spec = specn / fmaxf(negc, 1.0f);
    loss = neg_log_clamped(prec, valid && (sump > 0.0f)) +
           neg_log_clamped(rec, valid) +
           neg_log_clamped(spec, valid && (negc > 0.0f));
    validf = valid ? 1.0f : 0.0f;
  }
  loss = wave_reduce(loss);
  validf = wave_reduce(validf);
  if (lane == 0) out[0] = loss / validf;
}

extern "C" void kernel_launch(void* const* d_in, const int* in_sizes, int n_in,
                              void* d_out, int out_size, void* d_ws, size_t ws_size,
                              hipStream_t stream) {
  const float* pred = (const float*)d_in[0];
  const int* target = (const int*)d_in[1];
  const int N = in_sizes[1];  // voxel count; C = in_sizes[0]/N = 20
  const int NH = (N + HALF - 1) / HALF;     // 8192 half-tiles for N = 2^21
  const int HPB = (NH + NBLK - 1) / NBLK;   // 16 halves per block

  hipMemsetAsync(d_ws, 0, NSLOT * 64 * sizeof(float), stream);
  pass1<<<NBLK, NTHR, 0, stream>>>(pred, target, (float*)d_ws, N, HPB);
  pass2<<<1, 64, 0, stream>>>((const float*)d_ws, (float*)d_out);
}

// Round 6
// 280.208 us; speedup vs baseline: 1.5197x; 1.5197x over previous
//
#include <hip/hip_runtime.h>
#include <math.h>

#define NCLS 20
#define IGNORE_IDX 255
#define LOG2E 1.4426950408889634f
#define NTHR 256
#define NSLOT 32  // partial-sum slots (rows of 64 floats) to spread atomic chains

typedef float v4f __attribute__((ext_vector_type(4)));
typedef int v4i __attribute__((ext_vector_type(4)));

__device__ __forceinline__ float wave_reduce(float v) {
#pragma unroll
  for (int off = 32; off > 0; off >>= 1) v += __shfl_xor(v, off, 64);
  return v;
}

__device__ __forceinline__ float neg_log_clamped(float x, bool cond) {
  if (!cond) return 0.0f;
  float xs = fmaxf(x, 1e-38f);
  return fminf(-logf(xs), 100.0f);
}

// Layout of s_acc rows / ws columns: [0..19] sum_p, [20..39] nominator,
// [40..59] ct_count, [60..63] unused.
//
// r6 design notes:
//  - Empirical ladder r0-r5: ALL VGPR-dest variants plateau at 1.4-1.8 TB/s
//    delivered; r5's global_load_lds staging regressed 2x (barrier drains
//    the counted vmcnt queue -> latency-serial). Best = r0 (98.8us): the
//    DEEPEST per-wave load batch (20 x v4f back-to-back) wins despite AGPR
//    spill and 23% occupancy. Lever ranking: batch depth >> occupancy.
//  - The ~7 GB/s/CU plateau ~= 4KB outstanding/CU at ~600ns: suspected
//    per-CU L1/TCP miss-slot cap. Fix attempt: NONTEMPORAL loads on pred
//    (global_load_dwordx4 nt = L1 bypass; pred is read exactly once, L1
//    buys nothing). This is the round's hypothesis test.
//  - Second fix vs r0: the 20 wave-butterflies (120 dependent ds_swizzle
//    chains/thread) -> one fire-and-forget ds_add per class of the quad-dot
//    into s_acc[c][tid&31] (2-way aliasing = free, measured 0 conflicts).
//  - Keep r0's quad/thread, 2048 blocks, plain launch_bounds(256) (the
//    unconstrained allocator produced the best result; don't fight it).
__global__ __launch_bounds__(NTHR) void pass1(const float* __restrict__ pred,
                                              const int* __restrict__ target,
                                              float* __restrict__ ws, int N) {
  __shared__ float s_acc[3 * NCLS][32];
  const int tid = threadIdx.x;
  const int sl = tid & 31;

  {
    float* p = &s_acc[0][0];
    for (int i = tid; i < 3 * NCLS * 32; i += NTHR) p[i] = 0.0f;
  }
  __syncthreads();

  const int nq = N >> 2;
  const int q = blockIdx.x * NTHR + tid;  // one voxel-quad per thread
  const bool in = (q < nq);

  v4f e[NCLS];
  float w[4] = {0.0f, 0.0f, 0.0f, 0.0f};
  v4f pt = (v4f)(0.0f);
  v4i t4 = {IGNORE_IDX, IGNORE_IDX, IGNORE_IDX, IGNORE_IDX};
#pragma unroll
  for (int c = 0; c < NCLS; ++c) e[c] = (v4f)(0.0f);

  if (in) {
    const int n = q << 2;
    t4 = *reinterpret_cast<const v4i*>(target + n);
    v4f Z = (v4f)(0.0f);
#pragma unroll
    for (int c = 0; c < NCLS; ++c) {
      // nt load: L1 bypass (single-use stream), global_load_dwordx4 ... nt
      const v4f x = __builtin_nontemporal_load(
          reinterpret_cast<const v4f*>(pred + (size_t)c * N + n));
#pragma unroll
      for (int j = 0; j < 4; ++j) {
        e[c][j] = __builtin_amdgcn_exp2f(fminf(x[j], 80.0f) * LOG2E);
        Z[j] += e[c][j];
        pt[j] = (c == t4[j]) ? e[c][j] : pt[j];
      }
    }
#pragma unroll
    for (int j = 0; j < 4; ++j) {
      const bool msk = (t4[j] != IGNORE_IDX);
      const float r = __builtin_amdgcn_rcpf(Z[j]);
      w[j] = msk ? r : 0.0f;
    }
  }

  // sum_p: per-class quad-dot -> ONE fire-and-forget ds_add per class.
  // (replaces r0's 20 wave-butterflies = 120 dependent ds_swizzle chains)
  // !in threads have e=0,w=0 -> add 0; uniform, no divergence.
#pragma unroll
  for (int c = 0; c < NCLS; ++c) {
    const float s = e[c][0] * w[0] + e[c][1] * w[1] +
                    e[c][2] * w[2] + e[c][3] * w[3];
    atomicAdd(&s_acc[c][sl], s);
  }

  // nominator / ct_count via LDS atomics
  if (in) {
#pragma unroll
    for (int j = 0; j < 4; ++j) {
      if (t4[j] != IGNORE_IDX) {
        atomicAdd(&s_acc[NCLS + t4[j]][sl], pt[j] * w[j]);
        atomicAdd(&s_acc[2 * NCLS + t4[j]][sl], 1.0f);
      }
    }
  }
  __syncthreads();

  // block flush: 60 rows x 32 slots, rotated start -> distinct banks/lane.
  if (tid < 3 * NCLS) {
    const float* row = s_acc[tid];
    float v = 0.0f;
#pragma unroll
    for (int i = 0; i < 32; ++i) v += row[(i + tid) & 31];
    // relaxed global atomics; pass2 is a separate dispatch (kernel boundary
    // provides visibility). 32 slots -> chains of gridDim/32 per address.
    atomicAdd(&ws[(size_t)(blockIdx.x & (NSLOT - 1)) * 64 + tid], v);
  }
}

__global__ __launch_bounds__(64) void pass2(const float* __restrict__ ws,
                                            float* __restrict__ out) {
  __shared__ float s[64];
  const int lane = threadIdx.x;
  float a = 0.0f;
#pragma unroll
  for (int r = 0; r < NSLOT; ++r) a += ws[r * 64 + lane];  // 32 indep loads

  // n_masked = sum of ct_count columns (lanes 40..59), uniform collective
  const float n_masked =
      wave_reduce((lane >= 2 * NCLS && lane < 3 * NCLS) ? a : 0.0f);

  // LDS bounce for per-class gather — NO divergent cross-lane ops
  s[lane] = a;
  __syncthreads();

  float loss = 0.0f, validf = 0.0f;
  if (lane < NCLS) {
    const float sump = s[lane];
    const float nom = s[NCLS + lane];
    const float cnt = s[2 * NCLS + lane];
    const bool valid = cnt > 0.0f;
    const float prec = nom / fmaxf(sump, 1e-38f);
    const float rec = nom / fmaxf(cnt, 1.0f);
    const float negc = n_masked - cnt;
    const float specn = n_masked - sump - cnt + nom;
    const float spec = specn / fmaxf(negc, 1.0f);
    loss = neg_log_clamped(prec, valid && (sump > 0.0f)) +
           neg_log_clamped(rec, valid) +
           neg_log_clamped(spec, valid && (negc > 0.0f));
    validf = valid ? 1.0f : 0.0f;
  }
  loss = wave_reduce(loss);      // uniform: all 64 lanes participate
  validf = wave_reduce(validf);
  if (lane == 0) out[0] = loss / validf;
}

extern "C" void kernel_launch(void* const* d_in, const int* in_sizes, int n_in,
                              void* d_out, int out_size, void* d_ws, size_t ws_size,
                              hipStream_t stream) {
  const float* pred = (const float*)d_in[0];
  const int* target = (const int*)d_in[1];
  const int N = in_sizes[1];  // voxel count; C = in_sizes[0]/N = 20
  const int nq = N >> 2;
  const int nblk = (nq + NTHR - 1) / NTHR;  // 2048 for N = 2^21

  hipMemsetAsync(d_ws, 0, NSLOT * 64 * sizeof(float), stream);
  pass1<<<nblk, NTHR, 0, stream>>>(pred, target, (float*)d_ws, N);
  pass2<<<1, 64, 0, stream>>>((const float*)d_ws, (float*)d_out);
}